// Round 3
// baseline (3342.173 us; speedup 1.0000x reference)
//
#include <hip/hip_runtime.h>

#define N_PAPER  500000
#define N_AUTHOR 300000
#define N_INST   10000
#define E_CITES  2000000
#define E_WRITES 2000000
#define E_REV    2000000
#define E_AFF    500000
#define E_TOT    (E_CITES + E_WRITES + E_REV + E_AFF)   // 6,500,000

#define SLOT_CITES  0
#define SLOT_WRITES (N_PAPER)
#define SLOT_REV    (2 * N_PAPER)
#define SLOT_AFF    (2 * N_PAPER + N_AUTHOR)
#define NSLOT       (2 * N_PAPER + N_AUTHOR + N_INST)   // 1,310,000

// ---------------- float4 helpers ----------------
__device__ __forceinline__ float4 f4zero() { return make_float4(0.f, 0.f, 0.f, 0.f); }
__device__ __forceinline__ float4 f4add(float4 a, float4 b) {
    return make_float4(a.x + b.x, a.y + b.y, a.z + b.z, a.w + b.w);
}
__device__ __forceinline__ float4 f4scale(float4 a, float s) {
    return make_float4(a.x * s, a.y * s, a.z * s, a.w * s);
}
__device__ __forceinline__ float4 f4fma(float4 acc, float s, float4 w) {
    acc.x = fmaf(s, w.x, acc.x);
    acc.y = fmaf(s, w.y, acc.y);
    acc.z = fmaf(s, w.z, acc.z);
    acc.w = fmaf(s, w.w, acc.w);
    return acc;
}
__device__ __forceinline__ float4 f4relu(float4 a) {
    return make_float4(fmaxf(a.x, 0.f), fmaxf(a.y, 0.f), fmaxf(a.z, 0.f), fmaxf(a.w, 0.f));
}

// ---------------- CSR build ----------------
__global__ void count_edges(const int* __restrict__ cd, const int* __restrict__ wd,
                            const int* __restrict__ rd, const int* __restrict__ ad,
                            int* __restrict__ cnt) {
    int t = blockIdx.x * 256 + threadIdx.x;
    if (t >= E_TOT) return;
    int slot;
    if (t < E_CITES)                          slot = SLOT_CITES  + cd[t];
    else if (t < E_CITES + E_WRITES)          slot = SLOT_WRITES + wd[t - E_CITES];
    else if (t < E_CITES + E_WRITES + E_REV)  slot = SLOT_REV    + rd[t - (E_CITES + E_WRITES)];
    else                                      slot = SLOT_AFF    + ad[t - (E_CITES + E_WRITES + E_REV)];
    atomicAdd(&cnt[slot], 1);
}

// start[i] = contiguous segment allocated via wave-aggregated atomicAdd on pool.
__global__ void alloc_csr(const int* __restrict__ cnt, int* __restrict__ start,
                          int* __restrict__ cursor, int* __restrict__ pool) {
    int i = blockIdx.x * 256 + threadIdx.x;
    int deg = (i < NSLOT) ? cnt[i] : 0;
    int incl = deg;
    #pragma unroll
    for (int d = 1; d < 64; d <<= 1) {
        int v = __shfl_up(incl, d);
        if ((threadIdx.x & 63) >= d) incl += v;
    }
    int total = __shfl(incl, 63);
    int base = 0;
    if ((threadIdx.x & 63) == 63) base = atomicAdd(pool, total);
    base = __shfl(base, 63);
    if (i < NSLOT) {
        int s = base + incl - deg;
        start[i]  = s;
        cursor[i] = s;
    }
}

__global__ void fill_csr(const int* __restrict__ cs, const int* __restrict__ cd,
                         const int* __restrict__ wsrc, const int* __restrict__ wd,
                         const int* __restrict__ rs, const int* __restrict__ rd,
                         const int* __restrict__ asrc, const int* __restrict__ ad,
                         int* __restrict__ cursor, int* __restrict__ esrc) {
    int t = blockIdx.x * 256 + threadIdx.x;
    if (t >= E_TOT) return;
    int src, slot;
    if (t < E_CITES)                         { src = cs[t];                              slot = SLOT_CITES  + cd[t]; }
    else if (t < E_CITES + E_WRITES)         { int u = t - E_CITES;                      src = wsrc[u]; slot = SLOT_WRITES + wd[u]; }
    else if (t < E_CITES + E_WRITES + E_REV) { int u = t - (E_CITES + E_WRITES);         src = rs[u];   slot = SLOT_REV    + rd[u]; }
    else                                     { int u = t - (E_CITES + E_WRITES + E_REV); src = asrc[u]; slot = SLOT_AFF    + ad[u]; }
    int pos = atomicAdd(&cursor[slot], 1);
    esrc[pos] = src;
}

// ---------------- weight prep: concatenated [K][128] matrices + summed biases ----------------
__global__ void wprep(const float* __restrict__ Wl_c, const float* __restrict__ bl_c, const float* __restrict__ Wr_c,
                      const float* __restrict__ Wl_w, const float* __restrict__ bl_w, const float* __restrict__ Wr_w,
                      const float* __restrict__ Wl_r, const float* __restrict__ bl_r, const float* __restrict__ Wr_r,
                      const float* __restrict__ Wl_a, const float* __restrict__ bl_a, const float* __restrict__ Wr_a,
                      float* __restrict__ Wp, float* __restrict__ Wa, float* __restrict__ Wi,
                      float* __restrict__ bp, float* __restrict__ ba, float* __restrict__ bi) {
    int t = blockIdx.x * 256 + threadIdx.x;
    if (t < 384 * 128) {
        int k = t >> 7, j = t & 127;
        float v;
        if (k < 128)      v = Wl_c[t];
        else if (k < 256) v = Wl_w[(k - 128) * 128 + j];
        else              v = Wr_c[(k - 256) * 128 + j] + Wr_w[(k - 256) * 128 + j];
        Wp[t] = v;
    }
    if (t < 256 * 128) {
        int k = t >> 7, j = t & 127;
        Wa[t] = (k < 128) ? Wl_r[t] : Wr_r[(k - 128) * 128 + j];
        Wi[t] = (k < 128) ? Wl_a[t] : Wr_a[(k - 128) * 128 + j];
    }
    if (t < 128) {
        bp[t] = bl_c[t] + bl_w[t];
        ba[t] = bl_r[t];
        bi[t] = bl_a[t];
    }
}

// ---------------- fused gather-mean + GEMM + bias + relu ----------------
// Block: 256 threads, 32 output rows.
// Phase 1: 8 threads/row gather CSR neighbor means + x_dst row into LDS tile [32][K] (K=(NREL+1)*128).
// Phase 2: thread (rg=tid>>5, cg=tid&31) computes rows rg*4..rg*4+3, cols cg*4..cg*4+3 of out = tile @ W.
template <int NREL>
__global__ __launch_bounds__(256) void sage_fused(
        const float* __restrict__ xdst,
        const float* __restrict__ xs0, const float* __restrict__ xs1,
        int slotbase0, int slotbase1,
        const int* __restrict__ cnt, const int* __restrict__ start,
        const int* __restrict__ esrc,
        const float* __restrict__ W, const float* __restrict__ bias,
        float* __restrict__ out, int nrows) {
    const int K   = (NREL + 1) * 128;
    const int LDT = K + 4;                       // pad 4 floats: kills phase-1 write bank conflicts
    __shared__ float tile[32 * ((NREL + 1) * 128 + 4)];

    const int tid = threadIdx.x;
    // -------- phase 1: gather --------
    {
        const int r   = tid >> 3;
        const int sub = tid & 7;
        const int c0  = sub * 16;
        const int row = blockIdx.x * 32 + r;
        float* trow = &tile[r * LDT];
        if (row < nrows) {
            // relation 0 mean
            {
                int slot = slotbase0 + row;
                int c = cnt[slot], s = start[slot];
                float4 a0 = f4zero(), a1 = f4zero(), a2 = f4zero(), a3 = f4zero();
                for (int e = 0; e < c; ++e) {
                    int j = esrc[s + e];
                    const float4* p = (const float4*)(xs0 + (size_t)j * 128 + c0);
                    a0 = f4add(a0, p[0]); a1 = f4add(a1, p[1]);
                    a2 = f4add(a2, p[2]); a3 = f4add(a3, p[3]);
                }
                float sc = 1.0f / (float)max(c, 1);
                float4* d = (float4*)(trow + c0);
                d[0] = f4scale(a0, sc); d[1] = f4scale(a1, sc);
                d[2] = f4scale(a2, sc); d[3] = f4scale(a3, sc);
            }
            // relation 1 mean
            if (NREL == 2) {
                int slot = slotbase1 + row;
                int c = cnt[slot], s = start[slot];
                float4 a0 = f4zero(), a1 = f4zero(), a2 = f4zero(), a3 = f4zero();
                for (int e = 0; e < c; ++e) {
                    int j = esrc[s + e];
                    const float4* p = (const float4*)(xs1 + (size_t)j * 128 + c0);
                    a0 = f4add(a0, p[0]); a1 = f4add(a1, p[1]);
                    a2 = f4add(a2, p[2]); a3 = f4add(a3, p[3]);
                }
                float sc = 1.0f / (float)max(c, 1);
                float4* d = (float4*)(trow + 128 + c0);
                d[0] = f4scale(a0, sc); d[1] = f4scale(a1, sc);
                d[2] = f4scale(a2, sc); d[3] = f4scale(a3, sc);
            }
            // x_dst row
            {
                const float4* p = (const float4*)(xdst + (size_t)row * 128 + c0);
                float4* d = (float4*)(trow + NREL * 128 + c0);
                d[0] = p[0]; d[1] = p[1]; d[2] = p[2]; d[3] = p[3];
            }
        } else {
            // zero so phase 2 math stays finite (outputs are guarded anyway)
            float4* d0 = (float4*)(trow + c0);
            float4 z = f4zero();
            d0[0] = z; d0[1] = z; d0[2] = z; d0[3] = z;
            if (NREL == 2) {
                float4* d1 = (float4*)(trow + 128 + c0);
                d1[0] = z; d1[1] = z; d1[2] = z; d1[3] = z;
            }
            float4* d2 = (float4*)(trow + NREL * 128 + c0);
            d2[0] = z; d2[1] = z; d2[2] = z; d2[3] = z;
        }
    }
    __syncthreads();

    // -------- phase 2: GEMM from LDS --------
    {
        const int rg = tid >> 5;
        const int cg = tid & 31;
        float4 acc0 = f4zero(), acc1 = f4zero(), acc2 = f4zero(), acc3 = f4zero();
        const float* tA = &tile[(rg * 4) * LDT];
        #pragma unroll 4
        for (int k = 0; k < K; k += 4) {
            const float* wbase = W + (size_t)k * 128 + cg * 4;
            float4 w0 = *(const float4*)(wbase);
            float4 w1 = *(const float4*)(wbase + 128);
            float4 w2 = *(const float4*)(wbase + 256);
            float4 w3 = *(const float4*)(wbase + 384);
            float4 aA = *(const float4*)(tA + k);
            float4 aB = *(const float4*)(tA + LDT + k);
            float4 aC = *(const float4*)(tA + 2 * LDT + k);
            float4 aD = *(const float4*)(tA + 3 * LDT + k);
            acc0 = f4fma(acc0, aA.x, w0); acc0 = f4fma(acc0, aA.y, w1);
            acc0 = f4fma(acc0, aA.z, w2); acc0 = f4fma(acc0, aA.w, w3);
            acc1 = f4fma(acc1, aB.x, w0); acc1 = f4fma(acc1, aB.y, w1);
            acc1 = f4fma(acc1, aB.z, w2); acc1 = f4fma(acc1, aB.w, w3);
            acc2 = f4fma(acc2, aC.x, w0); acc2 = f4fma(acc2, aC.y, w1);
            acc2 = f4fma(acc2, aC.z, w2); acc2 = f4fma(acc2, aC.w, w3);
            acc3 = f4fma(acc3, aD.x, w0); acc3 = f4fma(acc3, aD.y, w1);
            acc3 = f4fma(acc3, aD.z, w2); acc3 = f4fma(acc3, aD.w, w3);
        }
        float4 b = *(const float4*)(bias + cg * 4);
        int row0 = blockIdx.x * 32 + rg * 4;
        if (row0 + 0 < nrows) *(float4*)(out + (size_t)(row0 + 0) * 128 + cg * 4) = f4relu(f4add(acc0, b));
        if (row0 + 1 < nrows) *(float4*)(out + (size_t)(row0 + 1) * 128 + cg * 4) = f4relu(f4add(acc1, b));
        if (row0 + 2 < nrows) *(float4*)(out + (size_t)(row0 + 2) * 128 + cg * 4) = f4relu(f4add(acc2, b));
        if (row0 + 3 < nrows) *(float4*)(out + (size_t)(row0 + 3) * 128 + cg * 4) = f4relu(f4add(acc3, b));
    }
}

// ---------------- host launch ----------------
extern "C" void kernel_launch(void* const* d_in, const int* in_sizes, int n_in,
                              void* d_out, int out_size, void* d_ws, size_t ws_size,
                              hipStream_t stream) {
    const float* x_paper  = (const float*)d_in[0];
    const float* x_author = (const float*)d_in[1];
    const float* x_inst   = (const float*)d_in[2];
    const int* cites_src  = (const int*)d_in[3];
    const int* cites_dst  = (const int*)d_in[4];
    const int* writes_src = (const int*)d_in[5];
    const int* writes_dst = (const int*)d_in[6];
    const int* rev_src    = (const int*)d_in[7];
    const int* rev_dst    = (const int*)d_in[8];
    const int* aff_src    = (const int*)d_in[9];
    const int* aff_dst    = (const int*)d_in[10];
    const float* Wl_c = (const float*)d_in[11];
    const float* bl_c = (const float*)d_in[12];
    const float* Wr_c = (const float*)d_in[13];
    const float* Wl_w = (const float*)d_in[14];
    const float* bl_w = (const float*)d_in[15];
    const float* Wr_w = (const float*)d_in[16];
    const float* Wl_r = (const float*)d_in[17];
    const float* bl_r = (const float*)d_in[18];
    const float* Wr_r = (const float*)d_in[19];
    const float* Wl_a = (const float*)d_in[20];
    const float* bl_a = (const float*)d_in[21];
    const float* Wr_a = (const float*)d_in[22];

    float* out = (float*)d_out;

    // ---- workspace layout (all 16B-aligned) ----
    char* ws = (char*)d_ws;
    size_t off = 0;
    int* cnt    = (int*)(ws + off); off += (size_t)NSLOT * 4;      // 5,240,000
    int* pool   = (int*)(ws + off); off += 32;
    int* start  = (int*)(ws + off); off += (size_t)NSLOT * 4;
    int* cursor = (int*)(ws + off); off += (size_t)NSLOT * 4;
    int* esrc   = (int*)(ws + off); off += (size_t)E_TOT * 4;      // 26,000,000
    float* Wp   = (float*)(ws + off); off += 384 * 128 * 4;
    float* Wa   = (float*)(ws + off); off += 256 * 128 * 4;
    float* Wi   = (float*)(ws + off); off += 256 * 128 * 4;
    float* bp   = (float*)(ws + off); off += 512;
    float* ba   = (float*)(ws + off); off += 512;
    float* bi   = (float*)(ws + off); off += 512;
    (void)ws_size; (void)out_size; (void)n_in; (void)in_sizes;

    // zero cnt + pool
    hipMemsetAsync(ws, 0, (size_t)NSLOT * 4 + 32, stream);

    const int eblocks = (E_TOT + 255) / 256;
    count_edges<<<eblocks, 256, 0, stream>>>(cites_dst, writes_dst, rev_dst, aff_dst, cnt);
    alloc_csr<<<(NSLOT + 255) / 256, 256, 0, stream>>>(cnt, start, cursor, pool);
    fill_csr<<<eblocks, 256, 0, stream>>>(cites_src, cites_dst, writes_src, writes_dst,
                                          rev_src, rev_dst, aff_src, aff_dst, cursor, esrc);
    wprep<<<(384 * 128 + 255) / 256, 256, 0, stream>>>(
        Wl_c, bl_c, Wr_c, Wl_w, bl_w, Wr_w, Wl_r, bl_r, Wr_r, Wl_a, bl_a, Wr_a,
        Wp, Wa, Wi, bp, ba, bi);

    // paper: [mean_cites | mean_writes | x_paper] @ Wp + bp, relu
    sage_fused<2><<<(N_PAPER + 31) / 32, 256, 0, stream>>>(
        x_paper, x_paper, x_author, SLOT_CITES, SLOT_WRITES,
        cnt, start, esrc, Wp, bp, out, N_PAPER);
    // author: [mean_rev | x_author] @ Wa + ba, relu
    sage_fused<1><<<(N_AUTHOR + 31) / 32, 256, 0, stream>>>(
        x_author, x_paper, nullptr, SLOT_REV, 0,
        cnt, start, esrc, Wa, ba, out + (size_t)N_PAPER * 128, N_AUTHOR);
    // inst: [mean_aff | x_inst] @ Wi + bi, relu
    sage_fused<1><<<(N_INST + 31) / 32, 256, 0, stream>>>(
        x_inst, x_author, nullptr, SLOT_AFF, 0,
        cnt, start, esrc, Wi, bi, out + (size_t)(N_PAPER + N_AUTHOR) * 128, N_INST);
}

// Round 7
// 3197.614 us; speedup vs baseline: 1.0452x; 1.0452x over previous
//
#include <hip/hip_runtime.h>

#define N_PAPER  500000
#define N_AUTHOR 300000
#define N_INST   10000
#define E_CITES  2000000
#define E_WRITES 2000000
#define E_REV    2000000
#define E_AFF    500000
#define E_TOT    (E_CITES + E_WRITES + E_REV + E_AFF)   // 6,500,000

#define SLOT_CITES  0
#define SLOT_WRITES (N_PAPER)
#define SLOT_REV    (2 * N_PAPER)
#define SLOT_AFF    (2 * N_PAPER + N_AUTHOR)
#define NSLOT       (2 * N_PAPER + N_AUTHOR + N_INST)   // 1,310,000

typedef short  bf16x8 __attribute__((ext_vector_type(8)));
typedef float  f32x4  __attribute__((ext_vector_type(4)));

// ---------------- bf16 split helpers ----------------
__device__ __forceinline__ unsigned short f2b(float f) {           // f32 -> bf16 RNE
    unsigned int u = __float_as_uint(f);
    unsigned int r = (u + 0x7FFFu + ((u >> 16) & 1u)) >> 16;
    return (unsigned short)r;
}
__device__ __forceinline__ float b2f(unsigned short h) {
    return __uint_as_float(((unsigned int)h) << 16);
}

// ---------------- CSR build (unchanged, known-correct) ----------------
__global__ void count_edges(const int* __restrict__ cd, const int* __restrict__ wd,
                            const int* __restrict__ rd, const int* __restrict__ ad,
                            int* __restrict__ cnt) {
    int t = blockIdx.x * 256 + threadIdx.x;
    if (t >= E_TOT) return;
    int slot;
    if (t < E_CITES)                          slot = SLOT_CITES  + cd[t];
    else if (t < E_CITES + E_WRITES)          slot = SLOT_WRITES + wd[t - E_CITES];
    else if (t < E_CITES + E_WRITES + E_REV)  slot = SLOT_REV    + rd[t - (E_CITES + E_WRITES)];
    else                                      slot = SLOT_AFF    + ad[t - (E_CITES + E_WRITES + E_REV)];
    atomicAdd(&cnt[slot], 1);
}

__global__ void alloc_csr(const int* __restrict__ cnt, int* __restrict__ start,
                          int* __restrict__ cursor, int* __restrict__ pool) {
    int i = blockIdx.x * 256 + threadIdx.x;
    int deg = (i < NSLOT) ? cnt[i] : 0;
    int incl = deg;
    #pragma unroll
    for (int d = 1; d < 64; d <<= 1) {
        int v = __shfl_up(incl, d);
        if ((threadIdx.x & 63) >= d) incl += v;
    }
    int total = __shfl(incl, 63);
    int base = 0;
    if ((threadIdx.x & 63) == 63) base = atomicAdd(pool, total);
    base = __shfl(base, 63);
    if (i < NSLOT) {
        int s = base + incl - deg;
        start[i]  = s;
        cursor[i] = s;
    }
}

__global__ void fill_csr(const int* __restrict__ cs, const int* __restrict__ cd,
                         const int* __restrict__ wsrc, const int* __restrict__ wd,
                         const int* __restrict__ rs, const int* __restrict__ rd,
                         const int* __restrict__ asrc, const int* __restrict__ ad,
                         int* __restrict__ cursor, int* __restrict__ esrc) {
    int t = blockIdx.x * 256 + threadIdx.x;
    if (t >= E_TOT) return;
    int src, slot;
    if (t < E_CITES)                         { src = cs[t];                              slot = SLOT_CITES  + cd[t]; }
    else if (t < E_CITES + E_WRITES)         { int u = t - E_CITES;                      src = wsrc[u]; slot = SLOT_WRITES + wd[u]; }
    else if (t < E_CITES + E_WRITES + E_REV) { int u = t - (E_CITES + E_WRITES);         src = rs[u];   slot = SLOT_REV    + rd[u]; }
    else                                     { int u = t - (E_CITES + E_WRITES + E_REV); src = asrc[u]; slot = SLOT_AFF    + ad[u]; }
    int pos = atomicAdd(&cursor[slot], 1);
    esrc[pos] = src;
}

// ---------------- weight prep: split-bf16 fragment-order W + summed biases ----------------
// Fragment layout for B-operand of mfma_f32_16x16x32_bf16:
//   granule g = (k/32)*512 + ((k/8)%4)*128 + col   (16B = 8 bf16, e = k%8)
//   lane l of coltile reads granule (kb*4 + (l>>4))*128 + col  -> 16B contiguous per lane.
__device__ __forceinline__ int frag_idx(int k, int col) {
    return (((k >> 5) * 4 + ((k >> 3) & 3)) * 128 + col) * 8 + (k & 7);
}

__global__ void wprep(const float* __restrict__ Wl_c, const float* __restrict__ bl_c, const float* __restrict__ Wr_c,
                      const float* __restrict__ Wl_w, const float* __restrict__ bl_w, const float* __restrict__ Wr_w,
                      const float* __restrict__ Wl_r, const float* __restrict__ bl_r, const float* __restrict__ Wr_r,
                      const float* __restrict__ Wl_a, const float* __restrict__ bl_a, const float* __restrict__ Wr_a,
                      unsigned short* __restrict__ Wp_hi, unsigned short* __restrict__ Wp_lo,
                      unsigned short* __restrict__ Wa_hi, unsigned short* __restrict__ Wa_lo,
                      unsigned short* __restrict__ Wi_hi, unsigned short* __restrict__ Wi_lo,
                      float* __restrict__ bp, float* __restrict__ ba, float* __restrict__ bi) {
    int t = blockIdx.x * 256 + threadIdx.x;
    if (t < 384 * 128) {   // paper, K = 384
        int k = t >> 7, j = t & 127;
        float v;
        if (k < 128)      v = Wl_c[t];
        else if (k < 256) v = Wl_w[(k - 128) * 128 + j];
        else              v = Wr_c[(k - 256) * 128 + j] + Wr_w[(k - 256) * 128 + j];
        unsigned short hi = f2b(v);
        unsigned short lo = f2b(v - b2f(hi));
        int idx = frag_idx(k, j);
        Wp_hi[idx] = hi; Wp_lo[idx] = lo;
    }
    if (t < 256 * 128) {   // author + inst, K = 256
        int k = t >> 7, j = t & 127;
        float va = (k < 128) ? Wl_r[t] : Wr_r[(k - 128) * 128 + j];
        float vi = (k < 128) ? Wl_a[t] : Wr_a[(k - 128) * 128 + j];
        int idx = frag_idx(k, j);
        unsigned short ha = f2b(va); Wa_hi[idx] = ha; Wa_lo[idx] = f2b(va - b2f(ha));
        unsigned short hx = f2b(vi); Wi_hi[idx] = hx; Wi_lo[idx] = f2b(vi - b2f(hx));
    }
    if (t < 128) {
        bp[t] = bl_c[t] + bl_w[t];
        ba[t] = bl_r[t];
        bi[t] = bl_a[t];
    }
}

// ---------------- fused gather-mean + split-bf16 MFMA GEMM + bias + relu ----------------
// Block: 256 threads (4 waves), 32 output rows, N=128 cols.
// Gather: wave-per-row; 64 lanes each hold cols (2*lane, 2*lane+1) of the row,
//   coalesced 512B loads per edge; split f32 -> bf16 hi/lo into XOR-swizzled LDS.
// MFMA: wave w owns cols [32w, 32w+32); 2 row-tiles x 2 col-tiles; 3-term split GEMM.
template <int NREL>
__global__ __launch_bounds__(256) void sage_mfma(
        const float* __restrict__ xdst,
        const float* __restrict__ xs0, const float* __restrict__ xs1,
        int slotbase0, int slotbase1,
        const int* __restrict__ cnt, const int* __restrict__ start,
        const int* __restrict__ esrc,
        const unsigned short* __restrict__ Wf_hi, const unsigned short* __restrict__ Wf_lo,
        const float* __restrict__ bias,
        float* __restrict__ out, int nrows) {
    constexpr int K  = (NREL + 1) * 128;
    constexpr int K2 = K * 2;          // row stride in bytes (bf16)
    constexpr int KB = K / 32;
    __shared__ unsigned short lds_hi[32 * K];
    __shared__ unsigned short lds_lo[32 * K];
    char* chi = (char*)lds_hi;
    char* clo = (char*)lds_lo;

    const int tid  = threadIdx.x;
    const int w    = tid >> 6;
    const int lane = tid & 63;

    // -------- phase 1: gather (wave-per-row) --------
    for (int i = 0; i < 8; ++i) {
        const int tr   = w * 8 + i;
        const int row  = blockIdx.x * 32 + tr;
        const int swz  = (tr & 7) << 4;
        const int kbyte = lane * 4;            // this lane's 4B (2 bf16) within a 128-col slab
        if (row < nrows) {
            #pragma unroll
            for (int rel = 0; rel < NREL; ++rel) {
                const float* xs = (rel == 0) ? xs0 : xs1;
                const int slot  = (rel == 0 ? slotbase0 : slotbase1) + row;
                const int c = cnt[slot], s = start[slot];
                float a0 = 0.f, a1 = 0.f;
                int e = 0;
                for (; e + 4 <= c; e += 4) {
                    int j0 = esrc[s + e], j1 = esrc[s + e + 1];
                    int j2 = esrc[s + e + 2], j3 = esrc[s + e + 3];
                    float2 v0 = *(const float2*)(xs + (size_t)j0 * 128 + lane * 2);
                    float2 v1 = *(const float2*)(xs + (size_t)j1 * 128 + lane * 2);
                    float2 v2 = *(const float2*)(xs + (size_t)j2 * 128 + lane * 2);
                    float2 v3 = *(const float2*)(xs + (size_t)j3 * 128 + lane * 2);
                    a0 += (v0.x + v1.x) + (v2.x + v3.x);
                    a1 += (v0.y + v1.y) + (v2.y + v3.y);
                }
                for (; e < c; ++e) {
                    int j = esrc[s + e];
                    float2 v = *(const float2*)(xs + (size_t)j * 128 + lane * 2);
                    a0 += v.x; a1 += v.y;
                }
                const float sc = 1.0f / (float)(c > 0 ? c : 1);
                a0 *= sc; a1 *= sc;
                unsigned short h0 = f2b(a0), h1 = f2b(a1);
                float l0 = a0 - b2f(h0), l1 = a1 - b2f(h1);
                int off = (tr * K2 + rel * 256 + kbyte) ^ swz;
                *(unsigned int*)(chi + off) = (unsigned int)h0 | ((unsigned int)h1 << 16);
                *(unsigned int*)(clo + off) = (unsigned int)f2b(l0) | ((unsigned int)f2b(l1) << 16);
            }
            {   // x_dst row
                float2 v = *(const float2*)(xdst + (size_t)row * 128 + lane * 2);
                unsigned short h0 = f2b(v.x), h1 = f2b(v.y);
                float l0 = v.x - b2f(h0), l1 = v.y - b2f(h1);
                int off = (tr * K2 + NREL * 256 + kbyte) ^ swz;
                *(unsigned int*)(chi + off) = (unsigned int)h0 | ((unsigned int)h1 << 16);
                *(unsigned int*)(clo + off) = (unsigned int)f2b(l0) | ((unsigned int)f2b(l1) << 16);
            }
        } else {
            #pragma unroll
            for (int rel = 0; rel <= NREL; ++rel) {
                int off = (tr * K2 + rel * 256 + kbyte) ^ swz;
                *(unsigned int*)(chi + off) = 0u;
                *(unsigned int*)(clo + off) = 0u;
            }
        }
    }
    __syncthreads();

    // -------- phase 2: split-bf16 MFMA GEMM --------
    const int l15 = lane & 15;
    const int lg  = lane >> 4;
    const int colbase = w * 32 + l15;              // col of col-tile 0 (ct=1 adds 16)
    const int aswz = (l15 & 7) << 4;               // rows l15 and l15+16 share (row&7)

    f32x4 acc00 = {0.f, 0.f, 0.f, 0.f};
    f32x4 acc01 = {0.f, 0.f, 0.f, 0.f};
    f32x4 acc10 = {0.f, 0.f, 0.f, 0.f};
    f32x4 acc11 = {0.f, 0.f, 0.f, 0.f};

    for (int kb = 0; kb < KB; ++kb) {
        const int ab  = kb * 64 + lg * 16;
        const int o0  = ((l15)      * K2 + ab) ^ aswz;
        const int o1  = ((l15 + 16) * K2 + ab) ^ aswz;
        bf16x8 a0h = *(const bf16x8*)(chi + o0);
        bf16x8 a1h = *(const bf16x8*)(chi + o1);
        bf16x8 a0l = *(const bf16x8*)(clo + o0);
        bf16x8 a1l = *(const bf16x8*)(clo + o1);

        const size_t g0 = ((size_t)(kb * 4 + lg) * 128 + colbase) * 8;
        const size_t g1 = g0 + 16 * 8;
        bf16x8 w0h = *(const bf16x8*)(Wf_hi + g0);
        bf16x8 w1h = *(const bf16x8*)(Wf_hi + g1);
        bf16x8 w0l = *(const bf16x8*)(Wf_lo + g0);
        bf16x8 w1l = *(const bf16x8*)(Wf_lo + g1);

        acc00 = __builtin_amdgcn_mfma_f32_16x16x32_bf16(a0h, w0h, acc00, 0, 0, 0);
        acc00 = __builtin_amdgcn_mfma_f32_16x16x32_bf16(a0l, w0h, acc00, 0, 0, 0);
        acc00 = __builtin_amdgcn_mfma_f32_16x16x32_bf16(a0h, w0l, acc00, 0, 0, 0);

        acc01 = __builtin_amdgcn_mfma_f32_16x16x32_bf16(a0h, w1h, acc01, 0, 0, 0);
        acc01 = __builtin_amdgcn_mfma_f32_16x16x32_bf16(a0l, w1h, acc01, 0, 0, 0);
        acc01 = __builtin_amdgcn_mfma_f32_16x16x32_bf16(a0h, w1l, acc01, 0, 0, 0);

        acc10 = __builtin_amdgcn_mfma_f32_16x16x32_bf16(a1h, w0h, acc10, 0, 0, 0);
        acc10 = __builtin_amdgcn_mfma_f32_16x16x32_bf16(a1l, w0h, acc10, 0, 0, 0);
        acc10 = __builtin_amdgcn_mfma_f32_16x16x32_bf16(a1h, w0l, acc10, 0, 0, 0);

        acc11 = __builtin_amdgcn_mfma_f32_16x16x32_bf16(a1h, w1h, acc11, 0, 0, 0);
        acc11 = __builtin_amdgcn_mfma_f32_16x16x32_bf16(a1l, w1h, acc11, 0, 0, 0);
        acc11 = __builtin_amdgcn_mfma_f32_16x16x32_bf16(a1h, w1l, acc11, 0, 0, 0);
    }

    // -------- epilogue: bias + relu, C/D layout col=lane&15, row=(lane>>4)*4+j --------
    const float b0 = bias[colbase];
    const float b1 = bias[colbase + 16];
    const int row0 = blockIdx.x * 32 + lg * 4;
    #pragma unroll
    for (int j = 0; j < 4; ++j) {
        int r = row0 + j;            // row-tile 0
        if (r < nrows) {
            out[(size_t)r * 128 + colbase]      = fmaxf(acc00[j] + b0, 0.f);
            out[(size_t)r * 128 + colbase + 16] = fmaxf(acc01[j] + b1, 0.f);
        }
        int r2 = r + 16;             // row-tile 1
        if (r2 < nrows) {
            out[(size_t)r2 * 128 + colbase]      = fmaxf(acc10[j] + b0, 0.f);
            out[(size_t)r2 * 128 + colbase + 16] = fmaxf(acc11[j] + b1, 0.f);
        }
    }
}

// ---------------- host launch ----------------
extern "C" void kernel_launch(void* const* d_in, const int* in_sizes, int n_in,
                              void* d_out, int out_size, void* d_ws, size_t ws_size,
                              hipStream_t stream) {
    const float* x_paper  = (const float*)d_in[0];
    const float* x_author = (const float*)d_in[1];
    const float* x_inst   = (const float*)d_in[2];
    const int* cites_src  = (const int*)d_in[3];
    const int* cites_dst  = (const int*)d_in[4];
    const int* writes_src = (const int*)d_in[5];
    const int* writes_dst = (const int*)d_in[6];
    const int* rev_src    = (const int*)d_in[7];
    const int* rev_dst    = (const int*)d_in[8];
    const int* aff_src    = (const int*)d_in[9];
    const int* aff_dst    = (const int*)d_in[10];
    const float* Wl_c = (const float*)d_in[11];
    const float* bl_c = (const float*)d_in[12];
    const float* Wr_c = (const float*)d_in[13];
    const float* Wl_w = (const float*)d_in[14];
    const float* bl_w = (const float*)d_in[15];
    const float* Wr_w = (const float*)d_in[16];
    const float* Wl_r = (const float*)d_in[17];
    const float* bl_r = (const float*)d_in[18];
    const float* Wr_r = (const float*)d_in[19];
    const float* Wl_a = (const float*)d_in[20];
    const float* bl_a = (const float*)d_in[21];
    const float* Wr_a = (const float*)d_in[22];

    float* out = (float*)d_out;

    // ---- workspace layout (16B-aligned) ----
    char* ws = (char*)d_ws;
    size_t off = 0;
    int* cnt    = (int*)(ws + off); off += (size_t)NSLOT * 4;
    int* pool   = (int*)(ws + off); off += 32;
    int* start  = (int*)(ws + off); off += (size_t)NSLOT * 4;
    int* cursor = (int*)(ws + off); off += (size_t)NSLOT * 4;
    int* esrc   = (int*)(ws + off); off += (size_t)E_TOT * 4;
    unsigned short* Wp_hi = (unsigned short*)(ws + off); off += 384 * 128 * 2;
    unsigned short* Wp_lo = (unsigned short*)(ws + off); off += 384 * 128 * 2;
    unsigned short* Wa_hi = (unsigned short*)(ws + off); off += 256 * 128 * 2;
    unsigned short* Wa_lo = (unsigned short*)(ws + off); off += 256 * 128 * 2;
    unsigned short* Wi_hi = (unsigned short*)(ws + off); off += 256 * 128 * 2;
    unsigned short* Wi_lo = (unsigned short*)(ws + off); off += 256 * 128 * 2;
    float* bp   = (float*)(ws + off); off += 512;
    float* ba   = (float*)(ws + off); off += 512;
    float* bi   = (float*)(ws + off); off += 512;
    (void)ws_size; (void)out_size; (void)n_in; (void)in_sizes;

    hipMemsetAsync(ws, 0, (size_t)NSLOT * 4 + 32, stream);

    const int eblocks = (E_TOT + 255) / 256;
    count_edges<<<eblocks, 256, 0, stream>>>(cites_dst, writes_dst, rev_dst, aff_dst, cnt);
    alloc_csr<<<(NSLOT + 255) / 256, 256, 0, stream>>>(cnt, start, cursor, pool);
    fill_csr<<<eblocks, 256, 0, stream>>>(cites_src, cites_dst, writes_src, writes_dst,
                                          rev_src, rev_dst, aff_src, aff_dst, cursor, esrc);
    wprep<<<(384 * 128 + 255) / 256, 256, 0, stream>>>(
        Wl_c, bl_c, Wr_c, Wl_w, bl_w, Wr_w, Wl_r, bl_r, Wr_r, Wl_a, bl_a, Wr_a,
        Wp_hi, Wp_lo, Wa_hi, Wa_lo, Wi_hi, Wi_lo, bp, ba, bi);

    // paper: [mean_cites | mean_writes | x_paper] @ Wp + bp, relu
    sage_mfma<2><<<(N_PAPER + 31) / 32, 256, 0, stream>>>(
        x_paper, x_paper, x_author, SLOT_CITES, SLOT_WRITES,
        cnt, start, esrc, Wp_hi, Wp_lo, bp, out, N_PAPER);
    // author: [mean_rev | x_author] @ Wa + ba, relu
    sage_mfma<1><<<(N_AUTHOR + 31) / 32, 256, 0, stream>>>(
        x_author, x_paper, nullptr, SLOT_REV, 0,
        cnt, start, esrc, Wa_hi, Wa_lo, ba, out + (size_t)N_PAPER * 128, N_AUTHOR);
    // inst: [mean_aff | x_inst] @ Wi + bi, relu
    sage_mfma<1><<<(N_INST + 31) / 32, 256, 0, stream>>>(
        x_inst, x_author, nullptr, SLOT_AFF, 0,
        cnt, start, esrc, Wi_hi, Wi_lo, bi, out + (size_t)(N_PAPER + N_AUTHOR) * 128, N_INST);
}

// Round 11
// 2793.053 us; speedup vs baseline: 1.1966x; 1.1448x over previous
//
#include <hip/hip_runtime.h>

#define N_PAPER  500000
#define N_AUTHOR 300000
#define N_INST   10000
#define E_CITES  2000000
#define E_WRITES 2000000
#define E_REV    2000000
#define E_AFF    500000
#define E_TOT    (E_CITES + E_WRITES + E_REV + E_AFF)   // 6,500,000

#define SLOT_CITES  0
#define SLOT_WRITES (N_PAPER)
#define SLOT_REV    (2 * N_PAPER)
#define SLOT_AFF    (2 * N_PAPER + N_AUTHOR)
#define NSLOT       (2 * N_PAPER + N_AUTHOR + N_INST)   // 1,310,000

typedef short  bf16x8 __attribute__((ext_vector_type(8)));
typedef float  f32x4  __attribute__((ext_vector_type(4)));

// ---------------- bf16 split helpers ----------------
__device__ __forceinline__ unsigned short f2b(float f) {           // f32 -> bf16 RNE
    unsigned int u = __float_as_uint(f);
    unsigned int r = (u + 0x7FFFu + ((u >> 16) & 1u)) >> 16;
    return (unsigned short)r;
}
__device__ __forceinline__ float b2f(unsigned short h) {
    return __uint_as_float(((unsigned int)h) << 16);
}

// ---------------- CSR build (unchanged, known-correct) ----------------
__global__ void count_edges(const int* __restrict__ cd, const int* __restrict__ wd,
                            const int* __restrict__ rd, const int* __restrict__ ad,
                            int* __restrict__ cnt) {
    int t = blockIdx.x * 256 + threadIdx.x;
    if (t >= E_TOT) return;
    int slot;
    if (t < E_CITES)                          slot = SLOT_CITES  + cd[t];
    else if (t < E_CITES + E_WRITES)          slot = SLOT_WRITES + wd[t - E_CITES];
    else if (t < E_CITES + E_WRITES + E_REV)  slot = SLOT_REV    + rd[t - (E_CITES + E_WRITES)];
    else                                      slot = SLOT_AFF    + ad[t - (E_CITES + E_WRITES + E_REV)];
    atomicAdd(&cnt[slot], 1);
}

__global__ void alloc_csr(const int* __restrict__ cnt, int* __restrict__ start,
                          int* __restrict__ cursor, int* __restrict__ pool) {
    int i = blockIdx.x * 256 + threadIdx.x;
    int deg = (i < NSLOT) ? cnt[i] : 0;
    int incl = deg;
    #pragma unroll
    for (int d = 1; d < 64; d <<= 1) {
        int v = __shfl_up(incl, d);
        if ((threadIdx.x & 63) >= d) incl += v;
    }
    int total = __shfl(incl, 63);
    int base = 0;
    if ((threadIdx.x & 63) == 63) base = atomicAdd(pool, total);
    base = __shfl(base, 63);
    if (i < NSLOT) {
        int s = base + incl - deg;
        start[i]  = s;
        cursor[i] = s;
    }
}

__global__ void fill_csr(const int* __restrict__ cs, const int* __restrict__ cd,
                         const int* __restrict__ wsrc, const int* __restrict__ wd,
                         const int* __restrict__ rs, const int* __restrict__ rd,
                         const int* __restrict__ asrc, const int* __restrict__ ad,
                         int* __restrict__ cursor, int* __restrict__ esrc) {
    int t = blockIdx.x * 256 + threadIdx.x;
    if (t >= E_TOT) return;
    int src, slot;
    if (t < E_CITES)                         { src = cs[t];                              slot = SLOT_CITES  + cd[t]; }
    else if (t < E_CITES + E_WRITES)         { int u = t - E_CITES;                      src = wsrc[u]; slot = SLOT_WRITES + wd[u]; }
    else if (t < E_CITES + E_WRITES + E_REV) { int u = t - (E_CITES + E_WRITES);         src = rs[u];   slot = SLOT_REV    + rd[u]; }
    else                                     { int u = t - (E_CITES + E_WRITES + E_REV); src = asrc[u]; slot = SLOT_AFF    + ad[u]; }
    int pos = atomicAdd(&cursor[slot], 1);
    esrc[pos] = src;
}

// ---------------- weight prep: split-bf16 fragment-order W + summed biases ----------------
// B-operand fragment layout of mfma_f32_16x16x32_bf16 (verified by round-7 pass):
//   granule (kb*4 + kgrp)*128 + col holds 8 bf16 (k = kb*32 + kgrp*8 + e).
__device__ __forceinline__ int frag_idx(int k, int col) {
    return (((k >> 5) * 4 + ((k >> 3) & 3)) * 128 + col) * 8 + (k & 7);
}

__global__ void wprep(const float* __restrict__ Wl_c, const float* __restrict__ bl_c, const float* __restrict__ Wr_c,
                      const float* __restrict__ Wl_w, const float* __restrict__ bl_w, const float* __restrict__ Wr_w,
                      const float* __restrict__ Wl_r, const float* __restrict__ bl_r, const float* __restrict__ Wr_r,
                      const float* __restrict__ Wl_a, const float* __restrict__ bl_a, const float* __restrict__ Wr_a,
                      unsigned short* __restrict__ Wp_hi, unsigned short* __restrict__ Wp_lo,
                      unsigned short* __restrict__ Wa_hi, unsigned short* __restrict__ Wa_lo,
                      unsigned short* __restrict__ Wi_hi, unsigned short* __restrict__ Wi_lo,
                      float* __restrict__ bp, float* __restrict__ ba, float* __restrict__ bi) {
    int t = blockIdx.x * 256 + threadIdx.x;
    if (t < 384 * 128) {   // paper, K = 384
        int k = t >> 7, j = t & 127;
        float v;
        if (k < 128)      v = Wl_c[t];
        else if (k < 256) v = Wl_w[(k - 128) * 128 + j];
        else              v = Wr_c[(k - 256) * 128 + j] + Wr_w[(k - 256) * 128 + j];
        unsigned short hi = f2b(v);
        unsigned short lo = f2b(v - b2f(hi));
        int idx = frag_idx(k, j);
        Wp_hi[idx] = hi; Wp_lo[idx] = lo;
    }
    if (t < 256 * 128) {   // author + inst, K = 256
        int k = t >> 7, j = t & 127;
        float va = (k < 128) ? Wl_r[t] : Wr_r[(k - 128) * 128 + j];
        float vi = (k < 128) ? Wl_a[t] : Wr_a[(k - 128) * 128 + j];
        int idx = frag_idx(k, j);
        unsigned short ha = f2b(va); Wa_hi[idx] = ha; Wa_lo[idx] = f2b(va - b2f(ha));
        unsigned short hx = f2b(vi); Wi_hi[idx] = hx; Wi_lo[idx] = f2b(vi - b2f(hx));
    }
    if (t < 128) {
        bp[t] = bl_c[t] + bl_w[t];
        ba[t] = bl_r[t];
        bi[t] = bl_a[t];
    }
}

// ---------------- fused gather-mean + split-bf16 MFMA GEMM + bias + relu ----------------
// Block: 1024 threads = 16 waves, 32 output rows, N=128 cols.
// Gather: 2 rows per wave (4x shorter serial chain than 8/wave); per relation-slab
//   edges are consumed in PREDICATED batches of 8 (8 index loads then 8 masked row
//   loads -> 2 serial latencies per batch instead of per edge).
// MFMA: wave w -> row-tile rt=w>>3 (16 rows), col-tile ct=w&7 (16 cols), 1 acc.
template <int NREL>
__global__ __launch_bounds__(1024, 8) void sage_mfma(
        const float* __restrict__ xdst,
        const float* __restrict__ xs0, const float* __restrict__ xs1,
        int slotbase0, int slotbase1,
        const int* __restrict__ cnt, const int* __restrict__ start,
        const int* __restrict__ esrc,
        const unsigned short* __restrict__ Wf_hi, const unsigned short* __restrict__ Wf_lo,
        const float* __restrict__ bias,
        float* __restrict__ out, int nrows) {
    constexpr int K  = (NREL + 1) * 128;
    constexpr int K2 = K * 2;          // row stride in bytes (bf16)
    constexpr int KB = K / 32;
    __shared__ unsigned short lds_hi[32 * K];
    __shared__ unsigned short lds_lo[32 * K];
    char* chi = (char*)lds_hi;
    char* clo = (char*)lds_lo;

    const int tid  = threadIdx.x;
    const int w    = tid >> 6;         // wave 0..15
    const int lane = tid & 63;

    // -------- phase 1: gather (2 rows per wave) --------
    #pragma unroll
    for (int i = 0; i < 2; ++i) {
        const int tr    = w * 2 + i;
        const int row   = blockIdx.x * 32 + tr;
        const int swz   = (tr & 7) << 4;
        const int kbyte = lane * 4;    // this lane's 4B (2 bf16) within a 128-col slab
        if (row < nrows) {
            #pragma unroll
            for (int rel = 0; rel < NREL; ++rel) {
                const float* xs = (rel == 0) ? xs0 : xs1;
                const int slot  = (rel == 0 ? slotbase0 : slotbase1) + row;
                const int c = cnt[slot], s = start[slot];
                float a0 = 0.f, a1 = 0.f;
                if (c > 0) {
                    for (int e0 = 0; e0 < c; e0 += 8) {
                        int jj[8];
                        #pragma unroll
                        for (int t = 0; t < 8; ++t) {
                            int e = e0 + t;
                            jj[t] = esrc[s + (e < c ? e : c - 1)];
                        }
                        #pragma unroll
                        for (int t = 0; t < 8; ++t) {
                            float2 v = *(const float2*)(xs + (size_t)jj[t] * 128 + lane * 2);
                            float m = (e0 + t < c) ? 1.f : 0.f;
                            a0 = fmaf(m, v.x, a0);
                            a1 = fmaf(m, v.y, a1);
                        }
                    }
                }
                const float sc = 1.0f / (float)(c > 0 ? c : 1);
                a0 *= sc; a1 *= sc;
                unsigned short h0 = f2b(a0), h1 = f2b(a1);
                float l0 = a0 - b2f(h0), l1 = a1 - b2f(h1);
                int off = (tr * K2 + rel * 256 + kbyte) ^ swz;
                *(unsigned int*)(chi + off) = (unsigned int)h0 | ((unsigned int)h1 << 16);
                *(unsigned int*)(clo + off) = (unsigned int)f2b(l0) | ((unsigned int)f2b(l1) << 16);
            }
            {   // x_dst row
                float2 v = *(const float2*)(xdst + (size_t)row * 128 + lane * 2);
                unsigned short h0 = f2b(v.x), h1 = f2b(v.y);
                float l0 = v.x - b2f(h0), l1 = v.y - b2f(h1);
                int off = (tr * K2 + NREL * 256 + kbyte) ^ swz;
                *(unsigned int*)(chi + off) = (unsigned int)h0 | ((unsigned int)h1 << 16);
                *(unsigned int*)(clo + off) = (unsigned int)f2b(l0) | ((unsigned int)f2b(l1) << 16);
            }
        } else {
            #pragma unroll
            for (int rel = 0; rel <= NREL; ++rel) {
                int off = (tr * K2 + rel * 256 + kbyte) ^ swz;
                *(unsigned int*)(chi + off) = 0u;
                *(unsigned int*)(clo + off) = 0u;
            }
        }
    }
    __syncthreads();

    // -------- phase 2: split-bf16 MFMA (wave w -> rt=w>>3, ct=w&7) --------
    const int l15 = lane & 15;
    const int lg  = lane >> 4;
    const int rt  = w >> 3;
    const int ct  = w & 7;
    const int colbase = ct * 16 + l15;
    const int arow = rt * 16 + l15;
    const int aswz = (arow & 7) << 4;

    f32x4 acc = {0.f, 0.f, 0.f, 0.f};
    for (int kb = 0; kb < KB; ++kb) {
        const int o = (arow * K2 + kb * 64 + lg * 16) ^ aswz;
        bf16x8 ah = *(const bf16x8*)(chi + o);
        bf16x8 al = *(const bf16x8*)(clo + o);
        const size_t g = ((size_t)(kb * 4 + lg) * 128 + colbase) * 8;
        bf16x8 wh = *(const bf16x8*)(Wf_hi + g);
        bf16x8 wl = *(const bf16x8*)(Wf_lo + g);
        acc = __builtin_amdgcn_mfma_f32_16x16x32_bf16(ah, wh, acc, 0, 0, 0);
        acc = __builtin_amdgcn_mfma_f32_16x16x32_bf16(al, wh, acc, 0, 0, 0);
        acc = __builtin_amdgcn_mfma_f32_16x16x32_bf16(ah, wl, acc, 0, 0, 0);
    }

    // -------- epilogue: bias + relu, C/D layout col=lane&15, row=(lane>>4)*4+j --------
    const float b0 = bias[colbase];
    const int row0 = blockIdx.x * 32 + rt * 16 + lg * 4;
    #pragma unroll
    for (int j = 0; j < 4; ++j) {
        int r = row0 + j;
        if (r < nrows) out[(size_t)r * 128 + colbase] = fmaxf(acc[j] + b0, 0.f);
    }
}

// ---------------- host launch ----------------
extern "C" void kernel_launch(void* const* d_in, const int* in_sizes, int n_in,
                              void* d_out, int out_size, void* d_ws, size_t ws_size,
                              hipStream_t stream) {
    const float* x_paper  = (const float*)d_in[0];
    const float* x_author = (const float*)d_in[1];
    const float* x_inst   = (const float*)d_in[2];
    const int* cites_src  = (const int*)d_in[3];
    const int* cites_dst  = (const int*)d_in[4];
    const int* writes_src = (const int*)d_in[5];
    const int* writes_dst = (const int*)d_in[6];
    const int* rev_src    = (const int*)d_in[7];
    const int* rev_dst    = (const int*)d_in[8];
    const int* aff_src    = (const int*)d_in[9];
    const int* aff_dst    = (const int*)d_in[10];
    const float* Wl_c = (const float*)d_in[11];
    const float* bl_c = (const float*)d_in[12];
    const float* Wr_c = (const float*)d_in[13];
    const float* Wl_w = (const float*)d_in[14];
    const float* bl_w = (const float*)d_in[15];
    const float* Wr_w = (const float*)d_in[16];
    const float* Wl_r = (const float*)d_in[17];
    const float* bl_r = (const float*)d_in[18];
    const float* Wr_r = (const float*)d_in[19];
    const float* Wl_a = (const float*)d_in[20];
    const float* bl_a = (const float*)d_in[21];
    const float* Wr_a = (const float*)d_in[22];

    float* out = (float*)d_out;

    // ---- workspace layout (16B-aligned) ----
    char* ws = (char*)d_ws;
    size_t off = 0;
    int* cnt    = (int*)(ws + off); off += (size_t)NSLOT * 4;
    int* pool   = (int*)(ws + off); off += 32;
    int* start  = (int*)(ws + off); off += (size_t)NSLOT * 4;
    int* cursor = (int*)(ws + off); off += (size_t)NSLOT * 4;
    int* esrc   = (int*)(ws + off); off += (size_t)E_TOT * 4;
    unsigned short* Wp_hi = (unsigned short*)(ws + off); off += 384 * 128 * 2;
    unsigned short* Wp_lo = (unsigned short*)(ws + off); off += 384 * 128 * 2;
    unsigned short* Wa_hi = (unsigned short*)(ws + off); off += 256 * 128 * 2;
    unsigned short* Wa_lo = (unsigned short*)(ws + off); off += 256 * 128 * 2;
    unsigned short* Wi_hi = (unsigned short*)(ws + off); off += 256 * 128 * 2;
    unsigned short* Wi_lo = (unsigned short*)(ws + off); off += 256 * 128 * 2;
    float* bp   = (float*)(ws + off); off += 512;
    float* ba   = (float*)(ws + off); off += 512;
    float* bi   = (float*)(ws + off); off += 512;
    (void)ws_size; (void)out_size; (void)n_in; (void)in_sizes;

    hipMemsetAsync(ws, 0, (size_t)NSLOT * 4 + 32, stream);

    const int eblocks = (E_TOT + 255) / 256;
    count_edges<<<eblocks, 256, 0, stream>>>(cites_dst, writes_dst, rev_dst, aff_dst, cnt);
    alloc_csr<<<(NSLOT + 255) / 256, 256, 0, stream>>>(cnt, start, cursor, pool);
    fill_csr<<<eblocks, 256, 0, stream>>>(cites_src, cites_dst, writes_src, writes_dst,
                                          rev_src, rev_dst, aff_src, aff_dst, cursor, esrc);
    wprep<<<(384 * 128 + 255) / 256, 256, 0, stream>>>(
        Wl_c, bl_c, Wr_c, Wl_w, bl_w, Wr_w, Wl_r, bl_r, Wr_r, Wl_a, bl_a, Wr_a,
        Wp_hi, Wp_lo, Wa_hi, Wa_lo, Wi_hi, Wi_lo, bp, ba, bi);

    // paper: [mean_cites | mean_writes | x_paper] @ Wp + bp, relu
    sage_mfma<2><<<(N_PAPER + 31) / 32, 1024, 0, stream>>>(
        x_paper, x_paper, x_author, SLOT_CITES, SLOT_WRITES,
        cnt, start, esrc, Wp_hi, Wp_lo, bp, out, N_PAPER);
    // author: [mean_rev | x_author] @ Wa + ba, relu
    sage_mfma<1><<<(N_AUTHOR + 31) / 32, 1024, 0, stream>>>(
        x_author, x_paper, nullptr, SLOT_REV, 0,
        cnt, start, esrc, Wa_hi, Wa_lo, ba, out + (size_t)N_PAPER * 128, N_AUTHOR);
    // inst: [mean_aff | x_inst] @ Wi + bi, relu
    sage_mfma<1><<<(N_INST + 31) / 32, 1024, 0, stream>>>(
        x_inst, x_author, nullptr, SLOT_AFF, 0,
        cnt, start, esrc, Wi_hi, Wi_lo, bi, out + (size_t)(N_PAPER + N_AUTHOR) * 128, N_INST);
}